// Round 3
// baseline (78.887 us; speedup 1.0000x reference)
//
#include <hip/hip_runtime.h>

// HistByProfMultiChannel: x (16,128,56,56) f32, hist_edges (128,10) f32,
// out (16,128,11) f32.
//
// R3: KDE via micro-histogram. Per (bt,c) block:
//   1) deposit 3136 pixels into a 512-bin LDS histogram with linear (CIC)
//      interpolation -- no transcendentals in the pixel loop.
//   2) convolve the 512 micro-bins with the 10 Gaussians + sigmoid tail
//      (512*12 = 6144 trans per block vs 37632 for direct evaluation).
// CIC error <= w^2/8 * max|g''| ~ 1.5e-3/pixel worst-case; threshold 12.88.

#define NE 10
#define NBINS 11
#define HW 3136
#define HW4 784   // HW / 4
#define NCH 128
#define MB 512    // micro-bins
#define MBI (MB / 256)

__global__ __launch_bounds__(256)
void hist_kernel(const float* __restrict__ x,
                 const float* __restrict__ edges,
                 float* __restrict__ out) {
    const int bc  = blockIdx.x;          // bt*NCH + c
    const int c   = bc & (NCH - 1);
    const int tid = threadIdx.x;

    __shared__ float hist[MB];
    __shared__ float red[4][NBINS];

    // Zero the micro-histogram.
    hist[tid]       = 0.0f;
    hist[tid + 256] = 0.0f;

    // Per-channel edges (block-uniform).
    float e[NE];
    #pragma unroll
    for (int j = 0; j < NE; ++j) e[j] = edges[c * NE + j];

    // Histogram range: [emin - pad, emax + pad]; pad covers both the widest
    // Gaussian support (13 sigma) and the sigmoid steepness (20 -> 0.5 pad
    // puts the tail error below 5e-5/pixel at the clamp point).
    float emin = e[0], emax = e[0], sigmax = 0.0f;
    #pragma unroll
    for (int j = 1; j < NE; ++j) {
        emin   = fminf(emin, e[j]);
        emax   = fmaxf(emax, e[j]);
        sigmax = fmaxf(sigmax, fabsf(e[j - 1] - e[j]) * (1.0f / 3.0f));
    }
    const float pad  = fmaxf(0.5f, 13.0f * sigmax + 1e-3f);
    const float lo   = emin - pad;
    const float hi   = emax + pad;
    const float wbin = (hi - lo) * (1.0f / MB);
    const float invw = (float)MB / (hi - lo);

    __syncthreads();   // hist zeroed

    // ---- Phase 1: deposit pixels (no transcendentals) ----
    const float4* xp = (const float4*)(x + (size_t)bc * HW);
    for (int i = tid; i < HW4; i += 256) {
        float4 p = xp[i];
        float vs[4] = {p.x, p.y, p.z, p.w};
        #pragma unroll
        for (int k = 0; k < 4; ++k) {
            float v   = fminf(fmaxf(vs[k], lo), hi);
            float pos = fmaf(v - lo, invw, -0.5f);
            pos = fminf(fmaxf(pos, 0.0f), (float)MB - 1.0005f);
            int   m = (int)pos;
            float f = pos - (float)m;
            atomicAdd(&hist[m],     1.0f - f);
            atomicAdd(&hist[m + 1], f);
        }
    }

    // Profile coefficients: exp(-0.5*((x-mu)/sig)^2) = exp2(A*x^2 + B*x + C).
    const float LOG2E = 1.4426950408889634f;
    float As[NE], Bs[NE], Cs[NE];
    {
        float mu  = e[0];
        float sig = (e[0] - e[1]) * (1.0f / 3.0f) + 1e-6f;
        float k   = -0.5f * LOG2E / (sig * sig);
        As[0] = k; Bs[0] = -2.0f * k * mu; Cs[0] = k * mu * mu;
    }
    #pragma unroll
    for (int j = 1; j < NE; ++j) {
        float mu  = (e[j - 1] + e[j]) * 0.5f;
        float sig = (e[j - 1] - e[j]) * (1.0f / 3.0f) + 1e-6f;
        float k   = -0.5f * LOG2E / (sig * sig);
        As[j] = k; Bs[j] = -2.0f * k * mu; Cs[j] = k * mu * mu;
    }
    const float sB = -20.0f * LOG2E;
    const float sC =  20.0f * LOG2E * e[NE - 1];

    __syncthreads();   // all deposits done

    // ---- Phase 2: convolve micro-histogram with the 11 profiles ----
    float acc[NBINS];
    #pragma unroll
    for (int j = 0; j < NBINS; ++j) acc[j] = 0.0f;

    #pragma unroll
    for (int ii = 0; ii < MBI; ++ii) {
        int   m = tid + ii * 256;
        float h = hist[m];
        if (h != 0.0f) {
            float xm = fmaf((float)m + 0.5f, wbin, lo);
            float x2 = xm * xm;
            #pragma unroll
            for (int j = 0; j < NE; ++j) {
                float arg = fmaf(As[j], x2, fmaf(Bs[j], xm, Cs[j]));
                acc[j] = fmaf(h, __builtin_amdgcn_exp2f(arg), acc[j]);
            }
            float den = 1.0f + __builtin_amdgcn_exp2f(fmaf(sB, xm, sC));
            acc[NE] = fmaf(h, __builtin_amdgcn_rcpf(den), acc[NE]);
        }
    }

    // Wave (64-lane) reduce each accumulator.
    #pragma unroll
    for (int j = 0; j < NBINS; ++j) {
        float a = acc[j];
        #pragma unroll
        for (int off = 32; off > 0; off >>= 1)
            a += __shfl_down(a, off, 64);
        acc[j] = a;
    }

    // Cross-wave reduce via LDS (4 waves x 11 bins).
    const int wave = tid >> 6;
    const int lane = tid & 63;
    if (lane == 0) {
        #pragma unroll
        for (int j = 0; j < NBINS; ++j) red[wave][j] = acc[j];
    }
    __syncthreads();
    if (tid < NBINS) {
        float s = red[0][tid] + red[1][tid] + red[2][tid] + red[3][tid];
        out[(size_t)bc * NBINS + tid] = s;
    }
}

extern "C" void kernel_launch(void* const* d_in, const int* in_sizes, int n_in,
                              void* d_out, int out_size, void* d_ws, size_t ws_size,
                              hipStream_t stream) {
    const float* x     = (const float*)d_in[0];
    const float* edges = (const float*)d_in[1];
    float* out         = (float*)d_out;
    hist_kernel<<<dim3(16 * NCH), dim3(256), 0, stream>>>(x, edges, out);
}

// Round 4
// 52.955 us; speedup vs baseline: 1.4897x; 1.4897x over previous
//
#include <hip/hip_runtime.h>

// HistByProfMultiChannel: x (16,128,56,56) f32, hist_edges (128,10) f32,
// out (16,128,11) f32.
//
// R4: micro-histogram KDE, contention-fixed.
//  - Pixels outside [lo,hi] are NOT deposited (R3 clamped them into the end
//    bins -> 20-way same-address ds_add serialization = the 77us).
//    v > hi contributes exactly +1 to the sigmoid bin (register count);
//    v < lo contributes ~0 everywhere (sigmoid(-10)=4.5e-5).
//  - Per-wave histogram replicas hist[4][512] (8 KB LDS) kill cross-wave
//    atomic contention; phase 2 sums the 4 replicas.
//  - Phase 2: 512 bins x (10 Gaussians as exp2(A*x^2+B*x+C) + sigmoid).

#define NE 10
#define NBINS 11
#define HW 3136
#define HW4 784   // HW / 4
#define NCH 128
#define MB 512    // micro-bins
#define NW 4      // waves per block

__global__ __launch_bounds__(256)
void hist_kernel(const float* __restrict__ x,
                 const float* __restrict__ edges,
                 float* __restrict__ out) {
    const int bc   = blockIdx.x;          // bt*NCH + c
    const int c    = bc & (NCH - 1);
    const int tid  = threadIdx.x;
    const int wave = tid >> 6;

    __shared__ float hist[NW][MB];
    __shared__ float red[NW][NBINS];

    // Zero all replicas (4*512 floats / 256 threads = 8 each).
    #pragma unroll
    for (int i = 0; i < (NW * MB) / 256; ++i)
        ((float*)hist)[tid + i * 256] = 0.0f;

    // Per-channel edges (block-uniform).
    float e[NE];
    #pragma unroll
    for (int j = 0; j < NE; ++j) e[j] = edges[c * NE + j];

    float emin = e[0], emax = e[0];
    float sigmax = fabsf(e[0] - e[1]) * (1.0f / 3.0f);
    #pragma unroll
    for (int j = 1; j < NE; ++j) {
        emin   = fminf(emin, e[j]);
        emax   = fmaxf(emax, e[j]);
        sigmax = fmaxf(sigmax, fabsf(e[j - 1] - e[j]) * (1.0f / 3.0f));
    }
    // pad >= 0.5 gives sigmoid saturation error <= 4.5e-5/px at the cuts and
    // covers >= 13 sigma of every Gaussian.
    const float pad  = fmaxf(0.5f, 13.0f * sigmax + 1e-3f);
    const float lo   = emin - pad;
    const float hi   = emax + pad;
    const float wbin = (hi - lo) * (1.0f / MB);
    const float invw = (float)MB / (hi - lo);

    __syncthreads();   // hist zeroed

    // ---- Phase 1: prefetch all pixels, deposit in-range ones ----
    const float4* xp = (const float4*)(x + (size_t)bc * HW);
    float4 p0 = xp[tid];
    float4 p1 = xp[tid + 256];
    float4 p2 = xp[tid + 512];
    const bool tail = tid < (HW4 - 768);   // 16 lanes
    float4 p3 = tail ? xp[768 + tid] : make_float4(lo - 1.f, lo - 1.f, lo - 1.f, lo - 1.f);

    float satCount = 0.0f;   // pixels past hi: sigmoid contributes exactly 1
    float* hrow = hist[wave];

    float vs[16] = {p0.x, p0.y, p0.z, p0.w, p1.x, p1.y, p1.z, p1.w,
                    p2.x, p2.y, p2.z, p2.w, p3.x, p3.y, p3.z, p3.w};
    #pragma unroll
    for (int k = 0; k < 16; ++k) {
        float v = vs[k];
        satCount += (v > hi) ? 1.0f : 0.0f;
        if (v >= lo && v <= hi) {
            float pos = fmaf(v - lo, invw, -0.5f);
            pos = fminf(fmaxf(pos, 0.0f), (float)MB - 1.0005f);
            int   m = (int)pos;
            float f = pos - (float)m;
            atomicAdd(&hrow[m],     1.0f - f);
            atomicAdd(&hrow[m + 1], f);
        }
    }

    // Profile coefficients: exp(-0.5*((x-mu)/sig)^2) = exp2(A*x^2 + B*x + C).
    const float LOG2E = 1.4426950408889634f;
    float As[NE], Bs[NE], Cs[NE];
    {
        float mu  = e[0];
        float sig = (e[0] - e[1]) * (1.0f / 3.0f) + 1e-6f;
        float k   = -0.5f * LOG2E / (sig * sig);
        As[0] = k; Bs[0] = -2.0f * k * mu; Cs[0] = k * mu * mu;
    }
    #pragma unroll
    for (int j = 1; j < NE; ++j) {
        float mu  = (e[j - 1] + e[j]) * 0.5f;
        float sig = (e[j - 1] - e[j]) * (1.0f / 3.0f) + 1e-6f;
        float k   = -0.5f * LOG2E / (sig * sig);
        As[j] = k; Bs[j] = -2.0f * k * mu; Cs[j] = k * mu * mu;
    }
    const float sB = -20.0f * LOG2E;
    const float sC =  20.0f * LOG2E * e[NE - 1];

    __syncthreads();   // all deposits done

    // ---- Phase 2: convolve micro-histogram with the 11 profiles ----
    float acc[NBINS];
    #pragma unroll
    for (int j = 0; j < NBINS; ++j) acc[j] = 0.0f;
    acc[NE] = satCount;

    #pragma unroll
    for (int ii = 0; ii < MB / 256; ++ii) {
        int   m = tid + ii * 256;
        float h = hist[0][m] + hist[1][m] + hist[2][m] + hist[3][m];
        if (h != 0.0f) {
            float xm = fmaf((float)m + 0.5f, wbin, lo);
            float x2 = xm * xm;
            #pragma unroll
            for (int j = 0; j < NE; ++j) {
                float arg = fmaf(As[j], x2, fmaf(Bs[j], xm, Cs[j]));
                acc[j] = fmaf(h, __builtin_amdgcn_exp2f(arg), acc[j]);
            }
            float den = 1.0f + __builtin_amdgcn_exp2f(fmaf(sB, xm, sC));
            acc[NE] = fmaf(h, __builtin_amdgcn_rcpf(den), acc[NE]);
        }
    }

    // Wave (64-lane) reduce each accumulator.
    #pragma unroll
    for (int j = 0; j < NBINS; ++j) {
        float a = acc[j];
        #pragma unroll
        for (int off = 32; off > 0; off >>= 1)
            a += __shfl_down(a, off, 64);
        acc[j] = a;
    }

    // Cross-wave reduce via LDS (4 waves x 11 bins).
    const int lane = tid & 63;
    if (lane == 0) {
        #pragma unroll
        for (int j = 0; j < NBINS; ++j) red[wave][j] = acc[j];
    }
    __syncthreads();
    if (tid < NBINS) {
        float s = red[0][tid] + red[1][tid] + red[2][tid] + red[3][tid];
        out[(size_t)bc * NBINS + tid] = s;
    }
}

extern "C" void kernel_launch(void* const* d_in, const int* in_sizes, int n_in,
                              void* d_out, int out_size, void* d_ws, size_t ws_size,
                              hipStream_t stream) {
    const float* x     = (const float*)d_in[0];
    const float* edges = (const float*)d_in[1];
    float* out         = (float*)d_out;
    hist_kernel<<<dim3(16 * NCH), dim3(256), 0, stream>>>(x, edges, out);
}

// Round 5
// 20.759 us; speedup vs baseline: 3.8002x; 2.5510x over previous
//
#include <hip/hip_runtime.h>

// HistByProfMultiChannel: x (16,128,56,56) f32, hist_edges (128,10) f32,
// out (16,128,11) f32.
//
// R5: direct evaluation + wave compaction.
//  - Only ~49% of N(0,1) pixels fall in [LO, HI] where any profile is
//    non-trivial. v >= HI: sigmoid contributes exactly 1 (register count).
//    v <= LO: everything ~0. Neither needs transcendentals.
//  - Active values are compacted across the wave into a 64-deep register
//    queue (1 VGPR, lane i = slot i) via ONE unguarded ds_permute per
//    candidate: active lane idx-th -> slot (pcnt+idx)&63, inactive rank-ri
//    -> slot (pcnt+cnt+ri)&63 (an exact permutation of 0..63, so no
//    collisions; dump slots are discarded by the lane<pcnt select).
//    The 12-transcendental pipeline runs only on FULL 64-lane batches.
//  - sched_barrier(0) after the 16 global loads stops the compiler from
//    sinking them into the loop (R4's VGPR=28 proved it had been sinking).

#define NE 10
#define NBINS 11
#define HW 3136
#define HW4 784
#define NCH 128

__device__ __forceinline__ float rfl(float xv) {
    return __int_as_float(__builtin_amdgcn_readfirstlane(__float_as_int(xv)));
}

struct Coef {
    float A[NE], B[NE], C[NE];
    float sB, sC;
};

// Evaluate all 11 profiles at v and accumulate with weight w.
__device__ __forceinline__ void process64(float v, float w, const Coef& co, float* acc) {
    float v2 = v * v;
    #pragma unroll
    for (int j = 0; j < NE; ++j) {
        float arg = fmaf(co.A[j], v2, fmaf(co.B[j], v, co.C[j]));
        acc[j] = fmaf(__builtin_amdgcn_exp2f(arg), w, acc[j]);
    }
    float den = 1.0f + __builtin_amdgcn_exp2f(fmaf(co.sB, v, co.sC));
    acc[NE] = fmaf(__builtin_amdgcn_rcpf(den), w, acc[NE]);
}

__global__ __launch_bounds__(256)
void hist_kernel(const float* __restrict__ x,
                 const float* __restrict__ edges,
                 float* __restrict__ out) {
    const int bc   = blockIdx.x;          // bt*NCH + c
    const int c    = bc & (NCH - 1);
    const int tid  = threadIdx.x;
    const int lane = tid & 63;
    const int wave = tid >> 6;

    const float LOG2E = 1.4426950408889634f;

    // Per-channel edges (block-uniform) -> SGPRs.
    float e[NE];
    #pragma unroll
    for (int j = 0; j < NE; ++j) e[j] = rfl(edges[c * NE + j]);

    // exp(-0.5*((v-mu)/sig)^2) = exp2(A*v^2 + B*v + C)
    Coef co;
    {
        float mu  = e[0];
        float sig = (e[0] - e[1]) * (1.0f / 3.0f) + 1e-6f;
        float k   = -0.5f * LOG2E / (sig * sig);
        co.A[0] = rfl(k); co.B[0] = rfl(-2.0f * k * mu); co.C[0] = rfl(k * mu * mu);
    }
    #pragma unroll
    for (int j = 1; j < NE; ++j) {
        float mu  = (e[j - 1] + e[j]) * 0.5f;
        float sig = (e[j - 1] - e[j]) * (1.0f / 3.0f) + 1e-6f;
        float k   = -0.5f * LOG2E / (sig * sig);
        co.A[j] = rfl(k); co.B[j] = rfl(-2.0f * k * mu); co.C[j] = rfl(k * mu * mu);
    }
    co.sB = rfl(-20.0f * LOG2E);
    co.sC = rfl(20.0f * LOG2E * e[NE - 1]);

    // Active window: outside it every Gaussian < e^-23 and sigmoid is 0 or 1.
    float emin = e[0], emax = e[0], sigmax = fabsf(e[0] - e[1]) * (1.0f / 3.0f);
    #pragma unroll
    for (int j = 1; j < NE; ++j) {
        emin   = fminf(emin, e[j]);
        emax   = fmaxf(emax, e[j]);
        sigmax = fmaxf(sigmax, fabsf(e[j - 1] - e[j]) * (1.0f / 3.0f));
    }
    const float LO = rfl(fminf(emin - 6.8f * sigmax - 0.01f, emax - 0.75f));
    const float HI = rfl(emax + fmaxf(6.8f * sigmax + 0.01f, 0.40f));

    // ---- 16 pixels per thread, loaded up front ----
    const float4* xp = (const float4*)(x + (size_t)bc * HW);
    float4 p0 = xp[tid];
    float4 p1 = xp[tid + 256];
    float4 p2 = xp[tid + 512];
    float4 p3;
    if (tid < (HW4 - 768)) p3 = xp[768 + tid];          // 16 lanes real
    else { p3.x = p3.y = p3.z = p3.w = LO - 1.0f; }     // sentinel: inactive
    __builtin_amdgcn_sched_barrier(0);  // keep loads above the loop

    float acc[NBINS];
    #pragma unroll
    for (int j = 0; j < NBINS; ++j) acc[j] = 0.0f;
    float satCnt = 0.0f;   // pixels >= HI: sigmoid == 1 exactly (to 1e-4)

    float pend = 0.0f;     // 64-deep queue, lane i holds slot i
    int   pcnt = 0;        // uniform queue count

    const float vs[16] = {p0.x, p0.y, p0.z, p0.w, p1.x, p1.y, p1.z, p1.w,
                          p2.x, p2.y, p2.z, p2.w, p3.x, p3.y, p3.z, p3.w};
    #pragma unroll
    for (int k = 0; k < 16; ++k) {
        float v = vs[k];
        satCnt += (v >= HI) ? 1.0f : 0.0f;
        bool act = (v > LO) && (v < HI);
        unsigned long long mask = __ballot(act);
        int cnt = __popcll(mask);
        int idx = __builtin_amdgcn_mbcnt_hi((unsigned)(mask >> 32),
                  __builtin_amdgcn_mbcnt_lo((unsigned)mask, 0u));  // actives below me
        int ri  = lane - idx;                                      // inactives below me
        int tgt = (pcnt + (act ? idx : cnt + ri)) & 63;            // permutation of 0..63
        float tmp = __int_as_float(
            __builtin_amdgcn_ds_permute(tgt << 2, __float_as_int(v)));
        if (pcnt + cnt >= 64) {          // wave-uniform branch
            float bv = (lane < pcnt) ? pend : tmp;   // full 64-batch
            process64(bv, 1.0f, co, acc);
            pend = tmp;                  // slots [0, pcnt+cnt-64) hold overflow
            pcnt = pcnt + cnt - 64;
        } else {
            pend = (lane < pcnt) ? pend : tmp;
            pcnt += cnt;
        }
    }
    // Drain the partial queue.
    if (pcnt > 0) {
        float mid = rfl(0.5f * (LO + HI));
        float bv  = (lane < pcnt) ? pend : mid;
        float w   = (lane < pcnt) ? 1.0f : 0.0f;
        process64(bv, w, co, acc);
    }
    acc[NE] += satCnt;

    // Wave (64-lane) reduce each accumulator.
    #pragma unroll
    for (int j = 0; j < NBINS; ++j) {
        float a = acc[j];
        #pragma unroll
        for (int off = 32; off > 0; off >>= 1)
            a += __shfl_down(a, off, 64);
        acc[j] = a;
    }

    // Cross-wave reduce via LDS (4 waves x 11 bins).
    __shared__ float red[4][NBINS];
    if (lane == 0) {
        #pragma unroll
        for (int j = 0; j < NBINS; ++j) red[wave][j] = acc[j];
    }
    __syncthreads();
    if (tid < NBINS) {
        float s = red[0][tid] + red[1][tid] + red[2][tid] + red[3][tid];
        out[(size_t)bc * NBINS + tid] = s;
    }
}

extern "C" void kernel_launch(void* const* d_in, const int* in_sizes, int n_in,
                              void* d_out, int out_size, void* d_ws, size_t ws_size,
                              hipStream_t stream) {
    const float* x     = (const float*)d_in[0];
    const float* edges = (const float*)d_in[1];
    float* out         = (float*)d_out;
    hist_kernel<<<dim3(16 * NCH), dim3(256), 0, stream>>>(x, edges, out);
}